// Round 1
// baseline (583.216 us; speedup 1.0000x reference)
//
#include <hip/hip_runtime.h>
#include <math.h>

// Problem constants
#define BB   128
#define NN   196
#define CC   768
#define HH   4
#define DD   192
#define TOK_PER   19267584   // 128*196*768
#define NROWS_ALL 75264      // 3*128*196
#define F4_ALL    14450688   // NROWS_ALL * 192
#define NUM_KEEP  118

// workspace layout (in floats)
#define OFF_QPART 0
#define SZ_QPART  (2*9*128*768)
#define OFF_VV    (OFF_QPART + SZ_QPART)
#define SZ_VV     (9*128*4*768)
#define OFF_BIAS  (OFF_VV + SZ_VV)
#define SZ_BIAS   (9*128*4)
#define OFF_GN    (OFF_BIAS + SZ_BIAS)
#define SZ_GN     (3*128*768)
#define OFF_LOG   (OFF_GN + SZ_GN)
#define SZ_LOG    (9*128*4*196)
#define OFF_COS   (OFF_LOG + SZ_LOG)

__device__ __forceinline__ float4 f4fma(float s, float4 b, float4 a) {
  a.x = fmaf(s, b.x, a.x); a.y = fmaf(s, b.y, a.y);
  a.z = fmaf(s, b.z, a.z); a.w = fmaf(s, b.w, a.w);
  return a;
}

// ---------------------------------------------------------------------------
// Normalize the 3 global vectors: gn[t][b][:] = g / max(||g||, 1e-12)
// grid 96 x 256 (one wave per row, 384 rows)
__global__ __launch_bounds__(256) void k_gnorm(const float* __restrict__ g0,
                                               const float* __restrict__ g1,
                                               const float* __restrict__ g2,
                                               float* __restrict__ gn) {
  int wid = (blockIdx.x * 256 + threadIdx.x) >> 6;
  int lane = threadIdx.x & 63;
  if (wid >= 384) return;
  int t = wid >> 7, b = wid & 127;
  const float* src = (t == 0) ? g0 : ((t == 1) ? g1 : g2);
  const float4* s4 = (const float4*)(src + (size_t)b * CC);
  float4 v0 = s4[lane], v1 = s4[lane + 64], v2 = s4[lane + 128];
  float ss = v0.x*v0.x + v0.y*v0.y + v0.z*v0.z + v0.w*v0.w
           + v1.x*v1.x + v1.y*v1.y + v1.z*v1.z + v1.w*v1.w
           + v2.x*v2.x + v2.y*v2.y + v2.z*v2.z + v2.w*v2.w;
  #pragma unroll
  for (int off = 32; off; off >>= 1) ss += __shfl_xor(ss, off);
  float inv = 1.0f / fmaxf(sqrtf(ss), 1e-12f);
  float4* d4 = (float4*)(gn + ((size_t)t * 128 + b) * CC);
  v0.x *= inv; v0.y *= inv; v0.z *= inv; v0.w *= inv;
  v1.x *= inv; v1.y *= inv; v1.z *= inv; v1.w *= inv;
  v2.x *= inv; v2.y *= inv; v2.z *= inv; v2.w *= inv;
  d4[lane] = v0; d4[lane + 64] = v1; d4[lane + 128] = v2;
}

// ---------------------------------------------------------------------------
// q partial GEMM: qpart[z][i][b][o] = sum_{c in half z} g_{gi}[b][c] * qw[i][o][c]
// grid (24, 9, 2), block 256. 64x64 tile, K=384 per split, chunks of 32.
__global__ __launch_bounds__(256) void k_qproj(const float* __restrict__ g0,
                                               const float* __restrict__ g1,
                                               const float* __restrict__ g2,
                                               const float* __restrict__ qw,
                                               float* __restrict__ qpart) {
  __shared__ __align__(16) float AsT[32 * 68];
  __shared__ __align__(16) float WsT[32 * 68];
  const int gtab[9] = {0, 1, 2, 1, 0, 2, 2, 0, 1};
  int i = blockIdx.y, z = blockIdx.z;
  int mt = blockIdx.x & 1, nt = blockIdx.x >> 1;
  int tid = threadIdx.x, tx = tid & 15, ty = tid >> 4;
  int gi = gtab[i];
  const float4* A4 = (const float4*)((gi == 0) ? g0 : ((gi == 1) ? g1 : g2));
  const float4* W4 = (const float4*)(qw + (size_t)i * CC * CC);
  float4 acc0 = {0,0,0,0}, acc1 = {0,0,0,0}, acc2 = {0,0,0,0}, acc3 = {0,0,0,0};
  int arow = mt * 64, wrow = nt * 64;
  int kb4 = z * 96;  // float4 units
  for (int kk = 0; kk < 12; kk++) {
    #pragma unroll
    for (int f = tid; f < 512; f += 256) {
      int r = f >> 3, k4 = f & 7;
      float4 va = A4[(size_t)(arow + r) * 192 + kb4 + kk * 8 + k4];
      float4 vw = W4[(size_t)(wrow + r) * 192 + kb4 + kk * 8 + k4];
      int kq = 4 * k4;
      AsT[(kq+0)*68 + r] = va.x; AsT[(kq+1)*68 + r] = va.y;
      AsT[(kq+2)*68 + r] = va.z; AsT[(kq+3)*68 + r] = va.w;
      WsT[(kq+0)*68 + r] = vw.x; WsT[(kq+1)*68 + r] = vw.y;
      WsT[(kq+2)*68 + r] = vw.z; WsT[(kq+3)*68 + r] = vw.w;
    }
    __syncthreads();
    #pragma unroll
    for (int k = 0; k < 32; k++) {
      float4 a = *(const float4*)&AsT[k * 68 + 4 * ty];
      float4 w = *(const float4*)&WsT[k * 68 + 4 * tx];
      acc0 = f4fma(a.x, w, acc0); acc1 = f4fma(a.y, w, acc1);
      acc2 = f4fma(a.z, w, acc2); acc3 = f4fma(a.w, w, acc3);
    }
    __syncthreads();
  }
  float* dst = qpart + (size_t)(z * 9 + i) * 128 * CC;
  int col = wrow + 4 * tx;
  int row = arow + 4 * ty;
  *(float4*)&dst[(size_t)(row + 0) * CC + col] = acc0;
  *(float4*)&dst[(size_t)(row + 1) * CC + col] = acc1;
  *(float4*)&dst[(size_t)(row + 2) * CC + col] = acc2;
  *(float4*)&dst[(size_t)(row + 3) * CC + col] = acc3;
}

// ---------------------------------------------------------------------------
// vv GEMM: vv[i][b][h][c] = sum_j (qpart0+qpart1+qb)[i][b][h*192+j] * kw[i][h*192+j][c]
// grid (24, 36), block 256. 64x64 tile, K=192, chunks of 32.
__global__ __launch_bounds__(256) void k_vvproj(const float* __restrict__ qpart,
                                                const float* __restrict__ qb,
                                                const float* __restrict__ kw,
                                                float* __restrict__ vvout) {
  __shared__ __align__(16) float AsT[32 * 68];
  __shared__ __align__(16) float Bs[32 * 68];
  int ih = blockIdx.y; int i = ih >> 2, h = ih & 3;
  int mt = blockIdx.x & 1, nt = blockIdx.x >> 1;
  int tid = threadIdx.x, tx = tid & 15, ty = tid >> 4;
  const float4* qp0 = (const float4*)qpart + (size_t)i * 128 * 192;
  const float4* qp1 = (const float4*)qpart + (size_t)(9 + i) * 128 * 192;
  const float4* qb4 = (const float4*)qb + (size_t)i * 192;
  const float4* B4  = (const float4*)(kw + (size_t)i * CC * CC);
  float4 acc0 = {0,0,0,0}, acc1 = {0,0,0,0}, acc2 = {0,0,0,0}, acc3 = {0,0,0,0};
  int arow = mt * 64;
  int bcol4 = nt * 16;
  for (int kk = 0; kk < 6; kk++) {
    #pragma unroll
    for (int f = tid; f < 512; f += 256) {
      // A chunk: 64 rows x 8 float4 (transposed into LDS)
      int r = f >> 3, k4 = f & 7;
      int colf4 = h * 48 + kk * 8 + k4;
      float4 va = qp0[(size_t)(arow + r) * 192 + colf4];
      float4 vb = qp1[(size_t)(arow + r) * 192 + colf4];
      float4 vq = qb4[colf4];
      va.x += vb.x + vq.x; va.y += vb.y + vq.y;
      va.z += vb.z + vq.z; va.w += vb.w + vq.w;
      int kq = 4 * k4;
      AsT[(kq+0)*68 + r] = va.x; AsT[(kq+1)*68 + r] = va.y;
      AsT[(kq+2)*68 + r] = va.z; AsT[(kq+3)*68 + r] = va.w;
      // B chunk: 32 k-rows x 16 float4 (natural layout)
      int rk = f >> 4, c4 = f & 15;
      float4 vB = B4[(size_t)(h * DD + kk * 32 + rk) * 192 + bcol4 + c4];
      *(float4*)&Bs[rk * 68 + 4 * c4] = vB;
    }
    __syncthreads();
    #pragma unroll
    for (int k = 0; k < 32; k++) {
      float4 a = *(const float4*)&AsT[k * 68 + 4 * ty];
      float4 bb = *(const float4*)&Bs[k * 68 + 4 * tx];
      acc0 = f4fma(a.x, bb, acc0); acc1 = f4fma(a.y, bb, acc1);
      acc2 = f4fma(a.z, bb, acc2); acc3 = f4fma(a.w, bb, acc3);
    }
    __syncthreads();
  }
  int col = nt * 64 + 4 * tx;
  int b0 = arow + 4 * ty;
  *(float4*)&vvout[((size_t)(i * 128 + b0 + 0) * 4 + h) * CC + col] = acc0;
  *(float4*)&vvout[((size_t)(i * 128 + b0 + 1) * 4 + h) * CC + col] = acc1;
  *(float4*)&vvout[((size_t)(i * 128 + b0 + 2) * 4 + h) * CC + col] = acc2;
  *(float4*)&vvout[((size_t)(i * 128 + b0 + 3) * 4 + h) * CC + col] = acc3;
}

// ---------------------------------------------------------------------------
// bias[i][b][h] = sum_j (q0+q1+qb)[i][b][h*192+j] * kb[i][h*192+j]
// grid 36, block 128
__global__ __launch_bounds__(128) void k_bias(const float* __restrict__ qpart,
                                              const float* __restrict__ qb,
                                              const float* __restrict__ kb,
                                              float* __restrict__ bias) {
  int ih = blockIdx.x; int i = ih >> 2, h = ih & 3;
  int b = threadIdx.x;
  const float* q0  = qpart + ((size_t)i * 128 + b) * CC + h * DD;
  const float* q1  = qpart + ((size_t)(9 + i) * 128 + b) * CC + h * DD;
  const float* qbb = qb + (size_t)i * CC + h * DD;
  const float* kbb = kb + (size_t)i * CC + h * DD;
  float s = 0.f;
  for (int j = 0; j < DD; j++) s = fmaf(q0[j] + q1[j] + qbb[j], kbb[j], s);
  bias[((size_t)i * 128 + b) * 4 + h] = s;
}

// ---------------------------------------------------------------------------
// Per-patch dots: for tensor t, batch b, rows n: 12 logits + 3 cos dots + self-norm.
// grid 768 (t,b,half), block 128. 45KB LDS of folded vectors.
__global__ __launch_bounds__(128) void k_dots(const float* __restrict__ rgb,
                                              const float* __restrict__ ni,
                                              const float* __restrict__ ti,
                                              const float* __restrict__ vv,
                                              const float* __restrict__ gn,
                                              const float* __restrict__ bias,
                                              float* __restrict__ logits,
                                              float* __restrict__ cosm) {
  __shared__ __align__(16) float V[15 * 768];
  int bid = blockIdx.x;
  int t = bid >> 8;            // /256
  int rem = bid & 255;
  int b = rem >> 1, half = rem & 1;
  const float* toks = (t == 0) ? rgb : ((t == 1) ? ni : ti);
  // stage 12 vv vectors + 3 normalized globals
  float4* V4 = (float4*)V;
  for (int f = threadIdx.x; f < 15 * 192; f += 128) {
    int v = f / 192, c4 = f - v * 192;
    const float4* src;
    if (v < 12) {
      int k = v >> 2, h = v & 3;
      src = (const float4*)(vv + (((size_t)(3 * t + k) * 128 + b) * 4 + h) * CC);
    } else {
      src = (const float4*)(gn + ((size_t)(v - 12) * 128 + b) * CC);
    }
    V4[f] = src[c4];
  }
  __syncthreads();
  int tid = threadIdx.x;
  if (tid >= 98) return;
  int n = half * 98 + tid;
  const float4* P4 = (const float4*)(toks + ((size_t)b * NN + n) * CC);
  float acc[16];
  #pragma unroll
  for (int v = 0; v < 16; v++) acc[v] = 0.f;
  #pragma unroll 2
  for (int c4 = 0; c4 < 192; c4++) {
    float4 p = P4[c4];
    #pragma unroll
    for (int v = 0; v < 15; v++) {
      float4 q = V4[v * 192 + c4];
      acc[v] += p.x * q.x + p.y * q.y + p.z * q.z + p.w * q.w;
    }
    acc[15] += p.x * p.x + p.y * p.y + p.z * p.z + p.w * p.w;
  }
  float invp = 1.0f / fmaxf(sqrtf(acc[15]), 1e-12f);
  const float scale = 0.07216878364870322f;  // 192^-0.5
  const int GI[3][3] = {{0, 1, 2}, {1, 0, 2}, {2, 0, 1}};
  #pragma unroll
  for (int k = 0; k < 3; k++) {
    int i = 3 * t + k;
    #pragma unroll
    for (int h = 0; h < 4; h++) {
      float bv = bias[((size_t)i * 128 + b) * 4 + h];
      logits[(((size_t)i * 128 + b) * 4 + h) * NN + n] = (acc[k * 4 + h] + bv) * scale;
    }
    cosm[((size_t)i * 128 + b) * NN + n] = acc[12 + GI[t][k]] * invp;
  }
}

// ---------------------------------------------------------------------------
// block reductions (256 threads, 4 waves)
__device__ __forceinline__ float bred_sum(float v, float* red) {
  #pragma unroll
  for (int off = 32; off; off >>= 1) v += __shfl_xor(v, off);
  int tid = threadIdx.x;
  if ((tid & 63) == 0) red[tid >> 6] = v;
  __syncthreads();
  v = (red[0] + red[1]) + (red[2] + red[3]);
  __syncthreads();
  return v;
}
__device__ __forceinline__ float bred_max(float v, float* red) {
  #pragma unroll
  for (int off = 32; off; off >>= 1) v = fmaxf(v, __shfl_xor(v, off));
  int tid = threadIdx.x;
  if ((tid & 63) == 0) red[tid >> 6] = v;
  __syncthreads();
  v = fmaxf(fmaxf(red[0], red[1]), fmaxf(red[2], red[3]));
  __syncthreads();
  return v;
}
__device__ __forceinline__ float bred_min(float v, float* red) {
  #pragma unroll
  for (int off = 32; off; off >>= 1) v = fminf(v, __shfl_xor(v, off));
  int tid = threadIdx.x;
  if ((tid & 63) == 0) red[tid >> 6] = v;
  __syncthreads();
  v = fminf(fminf(red[0], red[1]), fminf(red[2], red[3]));
  __syncthreads();
  return v;
}

// ---------------------------------------------------------------------------
// Softmax over n (12 rows), score combine, minmax, modal softmax mix, top-118 mask.
// grid (128, 3), block 256.
__global__ __launch_bounds__(256) void k_score(const float* __restrict__ logits,
                                               const float* __restrict__ cosm,
                                               const float* __restrict__ modal_w,
                                               float* __restrict__ outmask) {
  __shared__ float red[4];
  __shared__ float sfinal[196];
  int b = blockIdx.x, m = blockIdx.y;
  int tid = threadIdx.x;
  bool act = tid < NN;
  // w = softmax(modal_w[m])
  float w0 = modal_w[m * 3 + 0], w1 = modal_w[m * 3 + 1], w2 = modal_w[m * 3 + 2];
  float wm = fmaxf(w0, fmaxf(w1, w2));
  float e0 = expf(w0 - wm), e1 = expf(w1 - wm), e2 = expf(w2 - wm);
  float esum = e0 + e1 + e2;
  float wk[3] = {e0 / esum, e1 / esum, e2 / esum};
  float finalv = 0.f;
  for (int k = 0; k < 3; k++) {
    int i = 3 * m + k;
    float asum = 0.f;
    for (int h = 0; h < 4; h++) {
      float v = act ? logits[(((size_t)i * 128 + b) * 4 + h) * NN + tid] : -3.4e38f;
      float mx = bred_max(v, red);
      float e = act ? expf(v - mx) : 0.f;
      float s = bred_sum(e, red);
      asum += e / s;
    }
    float c = act ? cosm[((size_t)i * 128 + b) * NN + tid] : 0.f;
    float sc = c * asum * 0.25f;
    float mn = bred_min(act ? sc : 3.4e38f, red);
    float mx = bred_max(act ? sc : -3.4e38f, red);
    finalv += wk[k] * (sc - mn) / (mx - mn + 1e-8f);
  }
  if (act) sfinal[tid] = finalv;
  __syncthreads();
  if (act) {
    int cnt = 0;
    for (int j = 0; j < NN; j++) {
      float fj = sfinal[j];
      cnt += (fj > finalv) || (fj == finalv && j < tid);
    }
    outmask[((size_t)m * 128 + b) * NN + tid] = (cnt < NUM_KEEP) ? 1.0f : 0.0f;
  }
}

// ---------------------------------------------------------------------------
// Masked token write: out[r][c] = mask[r] ? tok[r][c] : 0
// grid 56448, block 256; one float4 per thread.
__global__ __launch_bounds__(256) void k_write(const float* __restrict__ rgb,
                                               const float* __restrict__ ni,
                                               const float* __restrict__ ti,
                                               const float* __restrict__ maskbuf,
                                               float* __restrict__ out) {
  int idx = blockIdx.x * 256 + threadIdx.x;   // < F4_ALL
  int r = idx / 192;
  int c4 = idx - r * 192;
  int m = r / 25088;
  int rb = r - m * 25088;
  float mv = maskbuf[r];
  const float* src = (m == 0) ? rgb : ((m == 1) ? ni : ti);
  float4 o = {0.f, 0.f, 0.f, 0.f};
  if (mv != 0.0f) o = ((const float4*)src)[(size_t)rb * 192 + c4];
  ((float4*)out)[idx] = o;
}

// ---------------------------------------------------------------------------
extern "C" void kernel_launch(void* const* d_in, const int* in_sizes, int n_in,
                              void* d_out, int out_size, void* d_ws, size_t ws_size,
                              hipStream_t stream) {
  const float* rgb = (const float*)d_in[0];
  const float* ni  = (const float*)d_in[1];
  const float* ti  = (const float*)d_in[2];
  const float* g0  = (const float*)d_in[3];
  const float* g1  = (const float*)d_in[4];
  const float* g2  = (const float*)d_in[5];
  const float* qw  = (const float*)d_in[6];
  const float* qb  = (const float*)d_in[7];
  const float* kw  = (const float*)d_in[8];
  const float* kb  = (const float*)d_in[9];
  const float* mw  = (const float*)d_in[10];

  float* ws    = (float*)d_ws;
  float* qpart = ws + OFF_QPART;
  float* vv    = ws + OFF_VV;
  float* bias  = ws + OFF_BIAS;
  float* gn    = ws + OFF_GN;
  float* logits= ws + OFF_LOG;
  float* cosm  = ws + OFF_COS;
  float* outf  = (float*)d_out;
  float* maskb = outf + (size_t)3 * TOK_PER;

  k_gnorm<<<96, 256, 0, stream>>>(g0, g1, g2, gn);
  k_qproj<<<dim3(24, 9, 2), 256, 0, stream>>>(g0, g1, g2, qw, qpart);
  k_vvproj<<<dim3(24, 36), 256, 0, stream>>>(qpart, qb, kw, vv);
  k_bias<<<36, 128, 0, stream>>>(qpart, qb, kb, bias);
  k_dots<<<768, 128, 0, stream>>>(rgb, ni, ti, vv, gn, bias, logits, cosm);
  k_score<<<dim3(128, 3), 256, 0, stream>>>(logits, cosm, mw, maskb);
  k_write<<<F4_ALL / 256, 256, 0, stream>>>(rgb, ni, ti, maskb, outf);
}

// Round 2
// 568.952 us; speedup vs baseline: 1.0251x; 1.0251x over previous
//
#include <hip/hip_runtime.h>
#include <math.h>

// Problem constants
#define BB   128
#define NN   196
#define CC   768
#define HH   4
#define DD   192
#define TOK_PER   19267584   // 128*196*768
#define NROWS_ALL 75264      // 3*128*196
#define F4_ALL    14450688   // NROWS_ALL * 192
#define NUM_KEEP  118
#define SCALE_D   0.07216878364870322f   // 192^-0.5

// workspace layout (in floats)
#define OFF_QPART 0
#define SZ_QPART  (2*9*128*768)
#define OFF_VV    (OFF_QPART + SZ_QPART)
#define SZ_VV     (9*128*4*768)
#define OFF_BIAS  (OFF_VV + SZ_VV)
#define SZ_BIAS   (9*128*4)
#define OFF_GN    (OFF_BIAS + SZ_BIAS)
#define SZ_GN     (3*128*768)
#define OFF_SC    (OFF_GN + SZ_GN)
#define SZ_SC     (3*128*196*16)

__device__ __forceinline__ float4 f4fma(float s, float4 b, float4 a) {
  a.x = fmaf(s, b.x, a.x); a.y = fmaf(s, b.y, a.y);
  a.z = fmaf(s, b.z, a.z); a.w = fmaf(s, b.w, a.w);
  return a;
}
__device__ __forceinline__ float f4dot(float4 p, float4 q) {
  return p.x*q.x + p.y*q.y + p.z*q.z + p.w*q.w;
}

// ---------------------------------------------------------------------------
// Normalize the 3 global vectors: gn[t][b][:] = g / max(||g||, 1e-12)
__global__ __launch_bounds__(256) void k_gnorm(const float* __restrict__ g0,
                                               const float* __restrict__ g1,
                                               const float* __restrict__ g2,
                                               float* __restrict__ gn) {
  int wid = (blockIdx.x * 256 + threadIdx.x) >> 6;
  int lane = threadIdx.x & 63;
  if (wid >= 384) return;
  int t = wid >> 7, b = wid & 127;
  const float* src = (t == 0) ? g0 : ((t == 1) ? g1 : g2);
  const float4* s4 = (const float4*)(src + (size_t)b * CC);
  float4 v0 = s4[lane], v1 = s4[lane + 64], v2 = s4[lane + 128];
  float ss = f4dot(v0,v0) + f4dot(v1,v1) + f4dot(v2,v2);
  #pragma unroll
  for (int off = 32; off; off >>= 1) ss += __shfl_xor(ss, off);
  float inv = 1.0f / fmaxf(sqrtf(ss), 1e-12f);
  float4* d4 = (float4*)(gn + ((size_t)t * 128 + b) * CC);
  v0.x *= inv; v0.y *= inv; v0.z *= inv; v0.w *= inv;
  v1.x *= inv; v1.y *= inv; v1.z *= inv; v1.w *= inv;
  v2.x *= inv; v2.y *= inv; v2.z *= inv; v2.w *= inv;
  d4[lane] = v0; d4[lane + 64] = v1; d4[lane + 128] = v2;
}

// ---------------------------------------------------------------------------
// q partial GEMM: qpart[z][i][b][o] = sum_{c in half z} g_{gi}[b][c] * qw[i][o][c]
__global__ __launch_bounds__(256) void k_qproj(const float* __restrict__ g0,
                                               const float* __restrict__ g1,
                                               const float* __restrict__ g2,
                                               const float* __restrict__ qw,
                                               float* __restrict__ qpart) {
  __shared__ __align__(16) float AsT[32 * 68];
  __shared__ __align__(16) float WsT[32 * 68];
  const int gtab[9] = {0, 1, 2, 1, 0, 2, 2, 0, 1};
  int i = blockIdx.y, z = blockIdx.z;
  int mt = blockIdx.x & 1, nt = blockIdx.x >> 1;
  int tid = threadIdx.x, tx = tid & 15, ty = tid >> 4;
  int gi = gtab[i];
  const float4* A4 = (const float4*)((gi == 0) ? g0 : ((gi == 1) ? g1 : g2));
  const float4* W4 = (const float4*)(qw + (size_t)i * CC * CC);
  float4 acc0 = {0,0,0,0}, acc1 = {0,0,0,0}, acc2 = {0,0,0,0}, acc3 = {0,0,0,0};
  int arow = mt * 64, wrow = nt * 64;
  int kb4 = z * 96;  // float4 units
  for (int kk = 0; kk < 12; kk++) {
    #pragma unroll
    for (int f = tid; f < 512; f += 256) {
      int r = f >> 3, k4 = f & 7;
      float4 va = A4[(size_t)(arow + r) * 192 + kb4 + kk * 8 + k4];
      float4 vw = W4[(size_t)(wrow + r) * 192 + kb4 + kk * 8 + k4];
      int kq = 4 * k4;
      AsT[(kq+0)*68 + r] = va.x; AsT[(kq+1)*68 + r] = va.y;
      AsT[(kq+2)*68 + r] = va.z; AsT[(kq+3)*68 + r] = va.w;
      WsT[(kq+0)*68 + r] = vw.x; WsT[(kq+1)*68 + r] = vw.y;
      WsT[(kq+2)*68 + r] = vw.z; WsT[(kq+3)*68 + r] = vw.w;
    }
    __syncthreads();
    #pragma unroll
    for (int k = 0; k < 32; k++) {
      float4 a = *(const float4*)&AsT[k * 68 + 4 * ty];
      float4 w = *(const float4*)&WsT[k * 68 + 4 * tx];
      acc0 = f4fma(a.x, w, acc0); acc1 = f4fma(a.y, w, acc1);
      acc2 = f4fma(a.z, w, acc2); acc3 = f4fma(a.w, w, acc3);
    }
    __syncthreads();
  }
  float* dst = qpart + (size_t)(z * 9 + i) * 128 * CC;
  int col = wrow + 4 * tx;
  int row = arow + 4 * ty;
  *(float4*)&dst[(size_t)(row + 0) * CC + col] = acc0;
  *(float4*)&dst[(size_t)(row + 1) * CC + col] = acc1;
  *(float4*)&dst[(size_t)(row + 2) * CC + col] = acc2;
  *(float4*)&dst[(size_t)(row + 3) * CC + col] = acc3;
}

// ---------------------------------------------------------------------------
// vv GEMM: vv[i][b][h][c] = sum_j (qpart0+qpart1+qb)[i][b][h*192+j] * kw[i][h*192+j][c]
__global__ __launch_bounds__(256) void k_vvproj(const float* __restrict__ qpart,
                                                const float* __restrict__ qb,
                                                const float* __restrict__ kw,
                                                float* __restrict__ vvout) {
  __shared__ __align__(16) float AsT[32 * 68];
  __shared__ __align__(16) float Bs[32 * 68];
  int ih = blockIdx.y; int i = ih >> 2, h = ih & 3;
  int mt = blockIdx.x & 1, nt = blockIdx.x >> 1;
  int tid = threadIdx.x, tx = tid & 15, ty = tid >> 4;
  const float4* qp0 = (const float4*)qpart + (size_t)i * 128 * 192;
  const float4* qp1 = (const float4*)qpart + (size_t)(9 + i) * 128 * 192;
  const float4* qb4 = (const float4*)qb + (size_t)i * 192;
  const float4* B4  = (const float4*)(kw + (size_t)i * CC * CC);
  float4 acc0 = {0,0,0,0}, acc1 = {0,0,0,0}, acc2 = {0,0,0,0}, acc3 = {0,0,0,0};
  int arow = mt * 64;
  int bcol4 = nt * 16;
  for (int kk = 0; kk < 6; kk++) {
    #pragma unroll
    for (int f = tid; f < 512; f += 256) {
      int r = f >> 3, k4 = f & 7;
      int colf4 = h * 48 + kk * 8 + k4;
      float4 va = qp0[(size_t)(arow + r) * 192 + colf4];
      float4 vb = qp1[(size_t)(arow + r) * 192 + colf4];
      float4 vq = qb4[colf4];
      va.x += vb.x + vq.x; va.y += vb.y + vq.y;
      va.z += vb.z + vq.z; va.w += vb.w + vq.w;
      int kq = 4 * k4;
      AsT[(kq+0)*68 + r] = va.x; AsT[(kq+1)*68 + r] = va.y;
      AsT[(kq+2)*68 + r] = va.z; AsT[(kq+3)*68 + r] = va.w;
      int rk = f >> 4, c4 = f & 15;
      float4 vB = B4[(size_t)(h * DD + kk * 32 + rk) * 192 + bcol4 + c4];
      *(float4*)&Bs[rk * 68 + 4 * c4] = vB;
    }
    __syncthreads();
    #pragma unroll
    for (int k = 0; k < 32; k++) {
      float4 a = *(const float4*)&AsT[k * 68 + 4 * ty];
      float4 bb = *(const float4*)&Bs[k * 68 + 4 * tx];
      acc0 = f4fma(a.x, bb, acc0); acc1 = f4fma(a.y, bb, acc1);
      acc2 = f4fma(a.z, bb, acc2); acc3 = f4fma(a.w, bb, acc3);
    }
    __syncthreads();
  }
  int col = nt * 64 + 4 * tx;
  int b0 = arow + 4 * ty;
  *(float4*)&vvout[((size_t)(i * 128 + b0 + 0) * 4 + h) * CC + col] = acc0;
  *(float4*)&vvout[((size_t)(i * 128 + b0 + 1) * 4 + h) * CC + col] = acc1;
  *(float4*)&vvout[((size_t)(i * 128 + b0 + 2) * 4 + h) * CC + col] = acc2;
  *(float4*)&vvout[((size_t)(i * 128 + b0 + 3) * 4 + h) * CC + col] = acc3;
}

// ---------------------------------------------------------------------------
// bias[i][b][h] = sum_j (q0+q1+qb)[i][b][h*192+j] * kb[i][h*192+j]
__global__ __launch_bounds__(128) void k_bias(const float* __restrict__ qpart,
                                              const float* __restrict__ qb,
                                              const float* __restrict__ kb,
                                              float* __restrict__ bias) {
  int ih = blockIdx.x; int i = ih >> 2, h = ih & 3;
  int b = threadIdx.x;
  const float* q0  = qpart + ((size_t)i * 128 + b) * CC + h * DD;
  const float* q1  = qpart + ((size_t)(9 + i) * 128 + b) * CC + h * DD;
  const float* qbb = qb + (size_t)i * CC + h * DD;
  const float* kbb = kb + (size_t)i * CC + h * DD;
  float s = 0.f;
  for (int j = 0; j < DD; j++) s = fmaf(q0[j] + q1[j] + qbb[j], kbb[j], s);
  bias[((size_t)i * 128 + b) * 4 + h] = s;
}

// ---------------------------------------------------------------------------
// k_dots v2: full-wave-per-row, V in registers, coalesced patch loads.
// Writes sc[t][b][n][16]: slots 0..11 = scaled+biased logits (k*4+h),
// 12..14 = cos for module k, 15 = unused.
// grid 768 = t*256 + b*2 + half; block 256 (4 waves); each wave does rows
// row_local = it*4 + w of its 98-row half.
__global__ __launch_bounds__(256, 2) void k_dots2(const float* __restrict__ rgb,
                                                  const float* __restrict__ ni,
                                                  const float* __restrict__ ti,
                                                  const float* __restrict__ vv,
                                                  const float* __restrict__ gn,
                                                  const float* __restrict__ bias,
                                                  float* __restrict__ sc) {
  __shared__ float red[4][64 * 17];
  int bid = blockIdx.x;
  int t = bid >> 8;
  int rem = bid & 255;
  int b = rem >> 1, half = rem & 1;
  int tid = threadIdx.x;
  int w = tid >> 6, lane = tid & 63;
  const float* toks = (t == 0) ? rgb : ((t == 1) ? ni : ti);
  int gi0, gi1, gi2;
  if (t == 0)      { gi0 = 0; gi1 = 1; gi2 = 2; }
  else if (t == 1) { gi0 = 1; gi1 = 0; gi2 = 2; }
  else             { gi0 = 2; gi1 = 0; gi2 = 1; }

  // V registers: 15 vectors x 3 float4 chunks (cols lane, lane+64, lane+128)
  float4 V[45];
  #pragma unroll
  for (int k = 0; k < 3; k++) {
    #pragma unroll
    for (int h = 0; h < 4; h++) {
      const float4* src = (const float4*)(vv + (((size_t)(3*t + k) * 128 + b) * 4 + h) * CC);
      int v = k * 4 + h;
      V[3*v + 0] = src[lane];
      V[3*v + 1] = src[lane + 64];
      V[3*v + 2] = src[lane + 128];
    }
  }
  {
    int gidx0 = gi0, gidx1 = gi1, gidx2 = gi2;
    const float4* s0 = (const float4*)(gn + ((size_t)gidx0 * 128 + b) * CC);
    const float4* s1 = (const float4*)(gn + ((size_t)gidx1 * 128 + b) * CC);
    const float4* s2 = (const float4*)(gn + ((size_t)gidx2 * 128 + b) * CC);
    V[36] = s0[lane]; V[37] = s0[lane + 64]; V[38] = s0[lane + 128];
    V[39] = s1[lane]; V[40] = s1[lane + 64]; V[41] = s1[lane + 128];
    V[42] = s2[lane]; V[43] = s2[lane + 64]; V[44] = s2[lane + 128];
  }

  // per-lane bias for epilogue (slot a = lane&15)
  int a_id = lane & 15;
  float bias_r = 0.f;
  if (a_id < 12)
    bias_r = bias[((size_t)(3*t + (a_id >> 2)) * 128 + b) * 4 + (a_id & 3)];

  float* myred = red[w];
  int s_grp = lane >> 4;           // 0..3
  int n0 = half * 98;

  // first row load (row_local = w, always < 98)
  const float4* pr0 = (const float4*)(toks + ((size_t)b * NN + n0 + w) * CC);
  float4 pc0 = pr0[lane], pc1 = pr0[lane + 64], pc2 = pr0[lane + 128];

  for (int it = 0; it < 25; it++) {
    int row_local = it * 4 + w;
    if (row_local >= 98) break;          // wave-uniform

    // ---- FMA phase: 16 partial dots over this lane's 12 columns
    float a[16];
    #pragma unroll
    for (int v = 0; v < 15; v++) {
      a[v] = f4dot(pc0, V[3*v]) + f4dot(pc1, V[3*v + 1]) + f4dot(pc2, V[3*v + 2]);
    }
    a[15] = f4dot(pc0, pc0) + f4dot(pc1, pc1) + f4dot(pc2, pc2);

    // ---- prefetch next row (covered by the reduce phase below)
    int rl_next = row_local + 4;
    float4 pn0, pn1, pn2;
    if (rl_next < 98) {
      const float4* pr = (const float4*)(toks + ((size_t)b * NN + n0 + rl_next) * CC);
      pn0 = pr[lane]; pn1 = pr[lane + 64]; pn2 = pr[lane + 128];
    }

    // ---- reduce via LDS transpose (wave-private, no barrier)
    #pragma unroll
    for (int v = 0; v < 16; v++) myred[lane * 17 + v] = a[v];
    __builtin_amdgcn_s_waitcnt(0);       // lgkmcnt(0): drain LDS writes (same wave)
    float part = 0.f;
    #pragma unroll
    for (int i = 0; i < 16; i++)
      part += myred[(s_grp * 16 + i) * 17 + a_id];
    part += __shfl_xor(part, 16, 64);
    part += __shfl_xor(part, 32, 64);
    // all lanes now hold the full sum for slot a_id

    float s15  = __shfl(part, 15, 64);   // self dot-product
    float invp = 1.0f / fmaxf(sqrtf(s15), 1e-12f);
    float res;
    if (a_id < 12)      res = (part + bias_r) * SCALE_D;
    else if (a_id < 15) res = part * invp;
    else                res = invp;

    if (lane < 16) {
      float* scrow = sc + (((size_t)t * 128 + b) * 196 + (n0 + row_local)) * 16;
      scrow[lane] = res;
    }
    pc0 = pn0; pc1 = pn1; pc2 = pn2;
  }
}

// ---------------------------------------------------------------------------
// block reductions (256 threads, 4 waves)
__device__ __forceinline__ float bred_sum(float v, float* red) {
  #pragma unroll
  for (int off = 32; off; off >>= 1) v += __shfl_xor(v, off);
  int tid = threadIdx.x;
  if ((tid & 63) == 0) red[tid >> 6] = v;
  __syncthreads();
  v = (red[0] + red[1]) + (red[2] + red[3]);
  __syncthreads();
  return v;
}
__device__ __forceinline__ float bred_max(float v, float* red) {
  #pragma unroll
  for (int off = 32; off; off >>= 1) v = fmaxf(v, __shfl_xor(v, off));
  int tid = threadIdx.x;
  if ((tid & 63) == 0) red[tid >> 6] = v;
  __syncthreads();
  v = fmaxf(fmaxf(red[0], red[1]), fmaxf(red[2], red[3]));
  __syncthreads();
  return v;
}
__device__ __forceinline__ float bred_min(float v, float* red) {
  #pragma unroll
  for (int off = 32; off; off >>= 1) v = fminf(v, __shfl_xor(v, off));
  int tid = threadIdx.x;
  if ((tid & 63) == 0) red[tid >> 6] = v;
  __syncthreads();
  v = fminf(fminf(red[0], red[1]), fminf(red[2], red[3]));
  __syncthreads();
  return v;
}

// ---------------------------------------------------------------------------
// Softmax over n (12 rows), score combine, minmax, modal softmax mix, top-118.
// grid (128, 3), block 256. Reads sc[t][b][n][16].
__global__ __launch_bounds__(256) void k_score(const float* __restrict__ sc,
                                               const float* __restrict__ modal_w,
                                               float* __restrict__ outmask) {
  __shared__ float red[4];
  __shared__ float sfinal[196];
  int b = blockIdx.x, m = blockIdx.y;
  int tid = threadIdx.x;
  bool act = tid < NN;
  const float* row = sc + (((size_t)m * 128 + b) * 196 + (act ? tid : 0)) * 16;
  float w0 = modal_w[m * 3 + 0], w1 = modal_w[m * 3 + 1], w2 = modal_w[m * 3 + 2];
  float wm = fmaxf(w0, fmaxf(w1, w2));
  float e0 = expf(w0 - wm), e1 = expf(w1 - wm), e2 = expf(w2 - wm);
  float esum = e0 + e1 + e2;
  float wk[3] = {e0 / esum, e1 / esum, e2 / esum};
  float finalv = 0.f;
  for (int k = 0; k < 3; k++) {
    float asum = 0.f;
    for (int h = 0; h < 4; h++) {
      float v = act ? row[k * 4 + h] : -3.4e38f;
      float mx = bred_max(v, red);
      float e = act ? expf(v - mx) : 0.f;
      float s = bred_sum(e, red);
      asum += e / s;
    }
    float c = act ? row[12 + k] : 0.f;
    float scv = c * asum * 0.25f;
    float mn = bred_min(act ? scv : 3.4e38f, red);
    float mx = bred_max(act ? scv : -3.4e38f, red);
    finalv += wk[k] * (scv - mn) / (mx - mn + 1e-8f);
  }
  if (act) sfinal[tid] = finalv;
  __syncthreads();
  if (act) {
    int cnt = 0;
    for (int j = 0; j < NN; j++) {
      float fj = sfinal[j];
      cnt += (fj > finalv) || (fj == finalv && j < tid);
    }
    outmask[((size_t)m * 128 + b) * NN + tid] = (cnt < NUM_KEEP) ? 1.0f : 0.0f;
  }
}

// ---------------------------------------------------------------------------
// Masked token write: out[r][c] = mask[r] ? tok[r][c] : 0
__global__ __launch_bounds__(256) void k_write(const float* __restrict__ rgb,
                                               const float* __restrict__ ni,
                                               const float* __restrict__ ti,
                                               const float* __restrict__ maskbuf,
                                               float* __restrict__ out) {
  int idx = blockIdx.x * 256 + threadIdx.x;   // < F4_ALL
  int r = idx / 192;
  int c4 = idx - r * 192;
  int m = r / 25088;
  int rb = r - m * 25088;
  float mv = maskbuf[r];
  const float* src = (m == 0) ? rgb : ((m == 1) ? ni : ti);
  float4 o = {0.f, 0.f, 0.f, 0.f};
  if (mv != 0.0f) o = ((const float4*)src)[(size_t)rb * 192 + c4];
  ((float4*)out)[idx] = o;
}

// ---------------------------------------------------------------------------
extern "C" void kernel_launch(void* const* d_in, const int* in_sizes, int n_in,
                              void* d_out, int out_size, void* d_ws, size_t ws_size,
                              hipStream_t stream) {
  const float* rgb = (const float*)d_in[0];
  const float* ni  = (const float*)d_in[1];
  const float* ti  = (const float*)d_in[2];
  const float* g0  = (const float*)d_in[3];
  const float* g1  = (const float*)d_in[4];
  const float* g2  = (const float*)d_in[5];
  const float* qw  = (const float*)d_in[6];
  const float* qb  = (const float*)d_in[7];
  const float* kw  = (const float*)d_in[8];
  const float* kb  = (const float*)d_in[9];
  const float* mw  = (const float*)d_in[10];

  float* ws    = (float*)d_ws;
  float* qpart = ws + OFF_QPART;
  float* vv    = ws + OFF_VV;
  float* bias  = ws + OFF_BIAS;
  float* gn    = ws + OFF_GN;
  float* sc    = ws + OFF_SC;
  float* outf  = (float*)d_out;
  float* maskb = outf + (size_t)3 * TOK_PER;

  k_gnorm<<<96, 256, 0, stream>>>(g0, g1, g2, gn);
  k_qproj<<<dim3(24, 9, 2), 256, 0, stream>>>(g0, g1, g2, qw, qpart);
  k_vvproj<<<dim3(24, 36), 256, 0, stream>>>(qpart, qb, kw, vv);
  k_bias<<<36, 128, 0, stream>>>(qpart, qb, kb, bias);
  k_dots2<<<768, 256, 0, stream>>>(rgb, ni, ti, vv, gn, bias, sc);
  k_score<<<dim3(128, 3), 256, 0, stream>>>(sc, mw, maskb);
  k_write<<<F4_ALL / 256, 256, 0, stream>>>(rgb, ni, ti, maskb, outf);
}